// Round 3
// baseline (613.243 us; speedup 1.0000x reference)
//
#include <hip/hip_runtime.h>
#include <stdint.h>

// W8A16 quantized linear as f16-MFMA GEMM with fp32 I/O (harness upcasts):
//   A   : float32 [M=8192][K=4096]   (fp16 activations upcast by harness)
//   Qw  : int32   [N=4096][K=4096]   (int8 weights widened by harness)
//   Sc  : float32 [N]                (per-output-channel scales)
//   Out : float32 [M][N],  Out[m][n] = Sc[n] * sum_k A[m][k]*Qw[n][k]
// m97-structure: 128x128 tile, BK=32, 4 waves (2x2), 4x4 16x16x32_f16 frags.
// A staged raw-fp32 via global_load_lds with 16B-slot XOR swizzle
// (phys_slot = s ^ (r&7); swizzled global source + swizzled ds_read,
// linear DMA dest — rule-21 both-sides pattern). B reg-staged + dequant
// to f16 LDS. Conversions exact: A is exact-fp16-valued, |q| <= 127.
// cvt_pkrtz returns __fp16 vectors -> bridge to _Float16 via bit_cast.

#define M_DIM 8192
#define N_DIM 4096
#define K_DIM 4096
#define BM 128
#define BN 128
#define BK 32
#define NKT (K_DIM / BK)   // 128 K-tiles

typedef _Float16 f16;
typedef f16 f16x8 __attribute__((ext_vector_type(8)));
typedef f16 f16x4 __attribute__((ext_vector_type(4)));
typedef f16 f16x2 __attribute__((ext_vector_type(2)));
typedef float f32x4 __attribute__((ext_vector_type(4)));

static __device__ __forceinline__ f16x2 cvt2(float a, float b) {
  return __builtin_bit_cast(f16x2, __builtin_amdgcn_cvt_pkrtz(a, b));
}

__global__ __launch_bounds__(256) void w8a16_gemm_kernel(
    const float* __restrict__ A,
    const int*   __restrict__ Qw,
    const float* __restrict__ Sc,
    float*       __restrict__ Out)
{
  // A tile: f32, logical [r:128][slot s:8] of 16B (4 f32) slots,
  // physical slot-in-row = s ^ (r&7). 2 x 16 KB.
  __shared__ __align__(16) float As[2][BM * BK];
  // B tile: f16 [128][32] (m97 layout). 2 x 8 KB.
  __shared__ __align__(16) f16 Bs[2][BN][BK];

  const int t    = threadIdx.x;
  const int lane = t & 63;
  const int wid  = t >> 6;
  const int wr   = wid >> 1;
  const int wc   = wid & 1;

  // XCD-aware bijective swizzle (nwg = 2048, %8 == 0 -> simple form)
  const int nwg = gridDim.x;
  const int cpx = nwg >> 3;
  const int bid = blockIdx.x;
  const int swz = (bid & 7) * cpx + (bid >> 3);
  const int tn  = swz & 31;   // 32 N-tiles
  const int tm  = swz >> 5;   // 64 M-tiles

  const size_t a_base = (size_t)tm * BM * K_DIM;
  const size_t b_base = (size_t)tn * BN * K_DIM;

  f32x4 acc[4][4] = {};

  // ---- A staging (global_load_lds, 4 chunks of 4 KB = 32 rows each) ----
  // chunk c, thread t -> phys flat slot f = c*256 + t; r = f>>3, s_phys = f&7,
  // holds logical slot s_log = s_phys ^ (r&7). c*32 is 0 mod 8 so r&7=(t>>3)&7.
  const int a_r    = t >> 3;                        // row within chunk (0..31)
  const int a_slog = (t & 7) ^ ((t >> 3) & 7);      // logical slot to fetch

  auto stageA = [&](int buf, int kt) {
    #pragma unroll
    for (int c = 0; c < 4; ++c) {
      const float* g = A + a_base + (size_t)(c * 32 + a_r) * K_DIM
                         + kt * BK + a_slog * 4;
      char* l = (char*)&As[buf][0] + c * 4096 + wid * 1024; // wave-uniform base
      __builtin_amdgcn_global_load_lds(
          (const __attribute__((address_space(1))) void*)g,
          (__attribute__((address_space(3))) void*)l, 16, 0, 0);
    }
  };

  // ---- B staging: int32 -> regs (coalesced) -> f16 LDS ----
  // chunk c covers elems c*1024 + t*4: r = c*32 + (t>>3), col = (t&7)*4
  const int b_r   = t >> 3;
  const int b_col = (t & 7) * 4;

  auto loadB = [&](int kt, int4* v) {
    #pragma unroll
    for (int c = 0; c < 4; ++c)
      v[c] = *(const int4*)(Qw + b_base + (size_t)(c * 32 + b_r) * K_DIM
                               + kt * BK + b_col);
  };

  auto writeB = [&](int buf, const int4* v) {
    #pragma unroll
    for (int c = 0; c < 4; ++c) {
      f16x2 lo = cvt2((float)v[c].x, (float)v[c].y);
      f16x2 hi = cvt2((float)v[c].z, (float)v[c].w);
      f16x4 pk = {lo.x, lo.y, hi.x, hi.y};
      *(f16x4*)&Bs[buf][c * 32 + b_r][b_col] = pk;
    }
  };

  auto compute = [&](int buf) {
    const int fr = lane & 15;
    const int q  = lane >> 4;       // k-quarter: k = q*8 + j
    f16x8 af[4], bf[4];
    #pragma unroll
    for (int i = 0; i < 4; ++i) {
      const int r = wr * 64 + i * 16 + fr;
      const float* base = &As[buf][0] + r * BK;
      const int s0 = q * 2;
      f32x4 a0 = *(const f32x4*)(base + ((s0     ^ (r & 7)) * 4));
      f32x4 a1 = *(const f32x4*)(base + (((s0+1) ^ (r & 7)) * 4));
      f16x2 p0 = cvt2(a0.x, a0.y);
      f16x2 p1 = cvt2(a0.z, a0.w);
      f16x2 p2 = cvt2(a1.x, a1.y);
      f16x2 p3 = cvt2(a1.z, a1.w);
      af[i] = (f16x8){p0.x, p0.y, p1.x, p1.y, p2.x, p2.y, p3.x, p3.y};
      bf[i] = *(const f16x8*)&Bs[buf][wc * 64 + i * 16 + fr][q * 8];
    }
    #pragma unroll
    for (int mi = 0; mi < 4; ++mi)
      #pragma unroll
      for (int ni = 0; ni < 4; ++ni)
        acc[mi][ni] = __builtin_amdgcn_mfma_f32_16x16x32_f16(
            af[mi], bf[ni], acc[mi][ni], 0, 0, 0);
  };

  // ---- main loop: double-buffered ----
  {
    int4 b0[4];
    stageA(0, 0);
    loadB(0, b0);
    writeB(0, b0);
  }
  __syncthreads();   // drains gload_lds vmcnt + ds_write before first read

  for (int kt = 0; kt < NKT; ++kt) {
    const int  buf  = kt & 1;
    const bool more = (kt + 1) < NKT;
    int4 nb[4];
    if (more) {
      stageA(buf ^ 1, kt + 1);   // async DMA into other buffer
      loadB(kt + 1, nb);         // int32 -> regs; latency hidden under MFMA
    }
    compute(buf);
    if (more) writeB(buf ^ 1, nb);
    __syncthreads();
  }

  // ---- epilogue: per-channel scale, fp32 store ----
  // C/D layout (m89/m91): col = lane&15 (n), row = (lane>>4)*4 + reg (m)
  const int fr = lane & 15;
  const int fq = lane >> 4;
  const int cb = tn * BN + wc * 64 + fr;
  const int rb = tm * BM + wr * 64 + fq * 4;
  #pragma unroll
  for (int ni = 0; ni < 4; ++ni) {
    const float s = Sc[cb + ni * 16];
    #pragma unroll
    for (int mi = 0; mi < 4; ++mi) {
      #pragma unroll
      for (int r = 0; r < 4; ++r) {
        Out[(size_t)(rb + mi * 16 + r) * N_DIM + (cb + ni * 16)] =
            acc[mi][ni][r] * s;
      }
    }
  }
}

extern "C" void kernel_launch(void* const* d_in, const int* in_sizes, int n_in,
                              void* d_out, int out_size, void* d_ws, size_t ws_size,
                              hipStream_t stream) {
  const float* A  = (const float*)d_in[0];   // fp32 (4,2048,4096)
  const int*   Qw = (const int*)d_in[1];     // int32 (4096,4096)
  const float* Sc = (const float*)d_in[2];   // fp32 (4096,1)
  float*       Out = (float*)d_out;          // fp32 (4,2048,4096)

  dim3 grid((M_DIM / BM) * (N_DIM / BN));    // 2048 blocks
  w8a16_gemm_kernel<<<grid, 256, 0, stream>>>(A, Qw, Sc, Out);
}

// Round 4
// 438.678 us; speedup vs baseline: 1.3979x; 1.3979x over previous
//
#include <hip/hip_runtime.h>
#include <stdint.h>

// W8A16 quantized linear, two-phase:
//   Pre-pass: A f32->f16 (64 MB), W = fp16(int32 q * scale) (32 MB) into d_ws.
//             (w = fp16(q*s) matches the reference's fp16 weight rounding.)
//   GEMM:     pure-f16 m97 structure — 128x128 tile, BK=32, 4 waves, 4x4
//             16x16x32_f16 frags, BOTH operands staged via global_load_lds
//             width=16 (no VALU in staging), double-buffered LDS.
// Fallback (ws_size < 96 MB): round-3 single-kernel path (in-loop dequant).

#define M_DIM 8192
#define N_DIM 4096
#define K_DIM 4096
#define BM 128
#define BN 128
#define BK 32
#define NKT (K_DIM / BK)

typedef _Float16 f16;
typedef f16 f16x8 __attribute__((ext_vector_type(8)));
typedef f16 f16x4 __attribute__((ext_vector_type(4)));
typedef f16 f16x2 __attribute__((ext_vector_type(2)));
typedef float f32x4 __attribute__((ext_vector_type(4)));

static __device__ __forceinline__ f16x2 cvt2(float a, float b) {
  return __builtin_bit_cast(f16x2, __builtin_amdgcn_cvt_pkrtz(a, b));
}

// ---------------- pre-pass kernels ----------------

// A: f32 -> f16, 8192*4096 = 33554432 elems; 2048 blocks x 256 thr x 8/iter x 8 iters
__global__ __launch_bounds__(256) void conv_a_kernel(
    const float* __restrict__ A, f16* __restrict__ Af)
{
  const size_t stride = (size_t)gridDim.x * blockDim.x;
  size_t i = (size_t)blockIdx.x * blockDim.x + threadIdx.x;
  const size_t n8 = (size_t)M_DIM * K_DIM / 8;
  for (; i < n8; i += stride) {
    const f32x4* p = (const f32x4*)(A + i * 8);
    f32x4 v0 = p[0], v1 = p[1];
    f16x2 a = cvt2(v0.x, v0.y), b = cvt2(v0.z, v0.w);
    f16x2 c = cvt2(v1.x, v1.y), d = cvt2(v1.z, v1.w);
    *(f16x8*)(Af + i * 8) = (f16x8){a.x, a.y, b.x, b.y, c.x, c.y, d.x, d.y};
  }
}

// W: one block per output row o: w[o][d] = fp16(q[o][d] * s[o]); 16 elems/thread
__global__ __launch_bounds__(256) void conv_b_kernel(
    const int* __restrict__ Qw, const float* __restrict__ Sc,
    f16* __restrict__ Wf)
{
  const int o = blockIdx.x;
  const int t = threadIdx.x;
  const float s = Sc[o];
  const int* q = Qw + (size_t)o * K_DIM + t * 16;
  f16* w = Wf + (size_t)o * K_DIM + t * 16;
  #pragma unroll
  for (int h = 0; h < 2; ++h) {
    int4 u0 = *(const int4*)(q + h * 8);
    int4 u1 = *(const int4*)(q + h * 8 + 4);
    f16x2 a = cvt2((float)u0.x * s, (float)u0.y * s);
    f16x2 b = cvt2((float)u0.z * s, (float)u0.w * s);
    f16x2 c = cvt2((float)u1.x * s, (float)u1.y * s);
    f16x2 d = cvt2((float)u1.z * s, (float)u1.w * s);
    *(f16x8*)(w + h * 8) = (f16x8){a.x, a.y, b.x, b.y, c.x, c.y, d.x, d.y};
  }
}

// ---------------- main GEMM (pure f16, m97 structure) ----------------

__global__ __launch_bounds__(256) void w8a16_gemm_f16_kernel(
    const f16* __restrict__ A,   // [M][K] f16
    const f16* __restrict__ W,   // [N][K] f16 (scale folded)
    float* __restrict__ Out)     // [M][N] f32
{
  __shared__ __align__(16) f16 As[2][BM][BK];
  __shared__ __align__(16) f16 Bs[2][BN][BK];

  const int t    = threadIdx.x;
  const int lane = t & 63;
  const int wid  = t >> 6;
  const int wr   = wid >> 1;
  const int wc   = wid & 1;

  // XCD-aware bijective swizzle (nwg = 2048, %8 == 0)
  const int nwg = gridDim.x;
  const int cpx = nwg >> 3;
  const int bid = blockIdx.x;
  const int swz = (bid & 7) * cpx + (bid >> 3);
  const int tn  = swz & 31;
  const int tm  = swz >> 5;

  const f16* a_src = A + (size_t)tm * BM * K_DIM;
  const f16* b_src = W + (size_t)tn * BN * K_DIM;

  f32x4 acc[4][4] = {};

  // staging: tile 128x32 f16 = 8 KB = 2 chunks of 4 KB (256 thr x 16 B)
  // thread t: row = c*64 + t/4, col = (t&3)*8 ; LDS byte = c*4096 + t*16
  const int s_row = t >> 2;
  const int s_col = (t & 3) * 8;

  auto stage = [&](const f16* src, f16* dst, int kt) {
    #pragma unroll
    for (int c = 0; c < 2; ++c) {
      const f16* g = src + (size_t)(c * 64 + s_row) * K_DIM + kt * BK + s_col;
      char* l = (char*)dst + c * 4096 + wid * 1024;  // wave-uniform base
      __builtin_amdgcn_global_load_lds(
          (const __attribute__((address_space(1))) void*)g,
          (__attribute__((address_space(3))) void*)l, 16, 0, 0);
    }
  };

  auto compute = [&](int buf) {
    const int fr = lane & 15;
    const int kk = (lane >> 4) * 8;
    f16x8 af[4], bf[4];
    #pragma unroll
    for (int i = 0; i < 4; ++i) {
      af[i] = *(const f16x8*)&As[buf][wr * 64 + i * 16 + fr][kk];
      bf[i] = *(const f16x8*)&Bs[buf][wc * 64 + i * 16 + fr][kk];
    }
    #pragma unroll
    for (int mi = 0; mi < 4; ++mi)
      #pragma unroll
      for (int ni = 0; ni < 4; ++ni)
        acc[mi][ni] = __builtin_amdgcn_mfma_f32_16x16x32_f16(
            af[mi], bf[ni], acc[mi][ni], 0, 0, 0);
  };

  stage(a_src, &As[0][0][0], 0);
  stage(b_src, &Bs[0][0][0], 0);
  __syncthreads();  // drains gload_lds vmcnt before first read

  for (int kt = 0; kt < NKT; ++kt) {
    const int  buf  = kt & 1;
    const bool more = (kt + 1) < NKT;
    if (more) {
      stage(a_src, &As[buf ^ 1][0][0], kt + 1);
      stage(b_src, &Bs[buf ^ 1][0][0], kt + 1);
    }
    compute(buf);
    __syncthreads();
  }

  // epilogue: C/D layout col = lane&15 (n), row = (lane>>4)*4 + reg (m)
  const int fr = lane & 15;
  const int fq = lane >> 4;
  const int cb = tn * BN + wc * 64 + fr;
  const int rb = tm * BM + wr * 64 + fq * 4;
  #pragma unroll
  for (int ni = 0; ni < 4; ++ni)
    #pragma unroll
    for (int mi = 0; mi < 4; ++mi)
      #pragma unroll
      for (int r = 0; r < 4; ++r)
        Out[(size_t)(rb + mi * 16 + r) * N_DIM + (cb + ni * 16)] =
            acc[mi][ni][r];
}

// ---------------- fallback: round-3 kernel (in-loop dequant) ----------------

__global__ __launch_bounds__(256) void w8a16_gemm_fb_kernel(
    const float* __restrict__ A, const int* __restrict__ Qw,
    const float* __restrict__ Sc, float* __restrict__ Out)
{
  __shared__ __align__(16) float As[2][BM * BK];
  __shared__ __align__(16) f16 Bs[2][BN][BK];

  const int t = threadIdx.x, lane = t & 63, wid = t >> 6;
  const int wr = wid >> 1, wc = wid & 1;
  const int nwg = gridDim.x, cpx = nwg >> 3, bid = blockIdx.x;
  const int swz = (bid & 7) * cpx + (bid >> 3);
  const int tn = swz & 31, tm = swz >> 5;
  const size_t a_base = (size_t)tm * BM * K_DIM;
  const size_t b_base = (size_t)tn * BN * K_DIM;
  f32x4 acc[4][4] = {};
  const int a_r = t >> 3;
  const int a_slog = (t & 7) ^ ((t >> 3) & 7);

  auto stageA = [&](int buf, int kt) {
    #pragma unroll
    for (int c = 0; c < 4; ++c) {
      const float* g = A + a_base + (size_t)(c * 32 + a_r) * K_DIM + kt * BK + a_slog * 4;
      char* l = (char*)&As[buf][0] + c * 4096 + wid * 1024;
      __builtin_amdgcn_global_load_lds(
          (const __attribute__((address_space(1))) void*)g,
          (__attribute__((address_space(3))) void*)l, 16, 0, 0);
    }
  };
  const int b_r = t >> 3, b_col = (t & 7) * 4;
  auto loadB = [&](int kt, int4* v) {
    #pragma unroll
    for (int c = 0; c < 4; ++c)
      v[c] = *(const int4*)(Qw + b_base + (size_t)(c * 32 + b_r) * K_DIM + kt * BK + b_col);
  };
  auto writeB = [&](int buf, const int4* v) {
    #pragma unroll
    for (int c = 0; c < 4; ++c) {
      f16x2 lo = cvt2((float)v[c].x, (float)v[c].y);
      f16x2 hi = cvt2((float)v[c].z, (float)v[c].w);
      *(f16x4*)&Bs[buf][c * 32 + b_r][b_col] = (f16x4){lo.x, lo.y, hi.x, hi.y};
    }
  };
  auto compute = [&](int buf) {
    const int fr = lane & 15, q = lane >> 4;
    f16x8 af[4], bf[4];
    #pragma unroll
    for (int i = 0; i < 4; ++i) {
      const int r = wr * 64 + i * 16 + fr;
      const float* base = &As[buf][0] + r * BK;
      const int s0 = q * 2;
      f32x4 a0 = *(const f32x4*)(base + ((s0 ^ (r & 7)) * 4));
      f32x4 a1 = *(const f32x4*)(base + (((s0 + 1) ^ (r & 7)) * 4));
      f16x2 p0 = cvt2(a0.x, a0.y), p1 = cvt2(a0.z, a0.w);
      f16x2 p2 = cvt2(a1.x, a1.y), p3 = cvt2(a1.z, a1.w);
      af[i] = (f16x8){p0.x, p0.y, p1.x, p1.y, p2.x, p2.y, p3.x, p3.y};
      bf[i] = *(const f16x8*)&Bs[buf][wc * 64 + i * 16 + fr][q * 8];
    }
    #pragma unroll
    for (int mi = 0; mi < 4; ++mi)
      #pragma unroll
      for (int ni = 0; ni < 4; ++ni)
        acc[mi][ni] = __builtin_amdgcn_mfma_f32_16x16x32_f16(
            af[mi], bf[ni], acc[mi][ni], 0, 0, 0);
  };

  { int4 b0[4]; stageA(0, 0); loadB(0, b0); writeB(0, b0); }
  __syncthreads();
  for (int kt = 0; kt < NKT; ++kt) {
    const int buf = kt & 1;
    const bool more = (kt + 1) < NKT;
    int4 nb[4];
    if (more) { stageA(buf ^ 1, kt + 1); loadB(kt + 1, nb); }
    compute(buf);
    if (more) writeB(buf ^ 1, nb);
    __syncthreads();
  }
  const int fr = lane & 15, fq = lane >> 4;
  const int cb = tn * BN + wc * 64 + fr;
  const int rb = tm * BM + wr * 64 + fq * 4;
  #pragma unroll
  for (int ni = 0; ni < 4; ++ni) {
    const float s = Sc[cb + ni * 16];
    #pragma unroll
    for (int mi = 0; mi < 4; ++mi)
      #pragma unroll
      for (int r = 0; r < 4; ++r)
        Out[(size_t)(rb + mi * 16 + r) * N_DIM + (cb + ni * 16)] =
            acc[mi][ni][r] * s;
  }
}

extern "C" void kernel_launch(void* const* d_in, const int* in_sizes, int n_in,
                              void* d_out, int out_size, void* d_ws, size_t ws_size,
                              hipStream_t stream) {
  const float* A  = (const float*)d_in[0];
  const int*   Qw = (const int*)d_in[1];
  const float* Sc = (const float*)d_in[2];
  float*       Out = (float*)d_out;

  const size_t a_bytes = (size_t)M_DIM * K_DIM * sizeof(f16);  // 64 MB
  const size_t w_bytes = (size_t)N_DIM * K_DIM * sizeof(f16);  // 32 MB

  if (ws_size >= a_bytes + w_bytes) {
    f16* Af = (f16*)d_ws;
    f16* Wf = (f16*)((char*)d_ws + a_bytes);
    conv_a_kernel<<<2048, 256, 0, stream>>>(A, Af);
    conv_b_kernel<<<N_DIM, 256, 0, stream>>>(Qw, Sc, Wf);
    dim3 grid((M_DIM / BM) * (N_DIM / BN));  // 2048
    w8a16_gemm_f16_kernel<<<grid, 256, 0, stream>>>(Af, Wf, Out);
  } else {
    dim3 grid((M_DIM / BM) * (N_DIM / BN));
    w8a16_gemm_fb_kernel<<<grid, 256, 0, stream>>>(A, Qw, Sc, Out);
  }
}

// Round 5
// 305.446 us; speedup vs baseline: 2.0077x; 1.4362x over previous
//
#include <hip/hip_runtime.h>
#include <stdint.h>

// W8A16 quantized linear, two-phase:
//   Pre-pass: A f32->f16 (64 MB), W = fp16(q*scale) (32 MB) into d_ws.
//   GEMM:     256x256 tile, BK=64, 8 waves (2M x 4N), 4-phase/K-tile schedule
//             with counted vmcnt (m201-style 8-phase over 2 K-tiles), raw
//             s_barrier, setprio MFMA clusters, XOR-swizzled LDS (T2),
//             both operands via global_load_lds width=16.
// Schedule ledger (per wave, steady state; HX = half-tile, 2 loads each):
//   entering G(kt): in-flight = [HA1(kt)]
//   p1 (A0,B0): reads HA0,HB0 (conf'd)   stage HA0(kt+1)
//   p2 (A0,B1): reads HB1 (conf'd)       stage HB0(kt+1); vmcnt(4) -> HA1(kt) ok
//   p3 (A1,B1): reads HA1 (now conf'd)   stage HB1(kt+1)
//   p4 (A1,B0): reg-reuse only           stage HA1(kt+1); vmcnt(2) -> kt+1's
//                                        HA0,HB0,HB1 ok; leftover [HA1(kt+1)]
// Stage targets always hit the non-read buffer; slot last read >=1 phase
// before its overwrite issue; barriers make the per-wave vmcnt a block-wide
// completion guarantee.

#define M_DIM 8192
#define N_DIM 4096
#define K_DIM 4096
#define BM 256
#define BN 256
#define BK 64
#define NKT (K_DIM / BK)   // 64 K-tiles

typedef _Float16 f16;
typedef f16 f16x8 __attribute__((ext_vector_type(8)));
typedef f16 f16x2 __attribute__((ext_vector_type(2)));
typedef float f32x4 __attribute__((ext_vector_type(4)));

static __device__ __forceinline__ f16x2 cvt2(float a, float b) {
  return __builtin_bit_cast(f16x2, __builtin_amdgcn_cvt_pkrtz(a, b));
}

// ---------------- pre-pass kernels ----------------

__global__ __launch_bounds__(256) void conv_a_kernel(
    const float* __restrict__ A, f16* __restrict__ Af)
{
  const size_t stride = (size_t)gridDim.x * blockDim.x;
  size_t i = (size_t)blockIdx.x * blockDim.x + threadIdx.x;
  const size_t n8 = (size_t)M_DIM * K_DIM / 8;
  for (; i < n8; i += stride) {
    const f32x4* p = (const f32x4*)(A + i * 8);
    f32x4 v0 = p[0], v1 = p[1];
    f16x2 a = cvt2(v0.x, v0.y), b = cvt2(v0.z, v0.w);
    f16x2 c = cvt2(v1.x, v1.y), d = cvt2(v1.z, v1.w);
    *(f16x8*)(Af + i * 8) = (f16x8){a.x, a.y, b.x, b.y, c.x, c.y, d.x, d.y};
  }
}

__global__ __launch_bounds__(256) void conv_b_kernel(
    const int* __restrict__ Qw, const float* __restrict__ Sc,
    f16* __restrict__ Wf)
{
  const int o = blockIdx.x;
  const int t = threadIdx.x;
  const float s = Sc[o];
  const int* q = Qw + (size_t)o * K_DIM + t * 16;
  f16* w = Wf + (size_t)o * K_DIM + t * 16;
  #pragma unroll
  for (int h = 0; h < 2; ++h) {
    int4 u0 = *(const int4*)(q + h * 8);
    int4 u1 = *(const int4*)(q + h * 8 + 4);
    f16x2 a = cvt2((float)u0.x * s, (float)u0.y * s);
    f16x2 b = cvt2((float)u0.z * s, (float)u0.w * s);
    f16x2 c = cvt2((float)u1.x * s, (float)u1.y * s);
    f16x2 d = cvt2((float)u1.z * s, (float)u1.w * s);
    *(f16x8*)(w + h * 8) = (f16x8){a.x, a.y, b.x, b.y, c.x, c.y, d.x, d.y};
  }
}

// ---------------- main GEMM: 256^2, BK=64, 8 waves, phase-split ----------------

#define BARX() __builtin_amdgcn_s_barrier()
#define LGKM0() do { asm volatile("s_waitcnt lgkmcnt(0)" ::: "memory"); \
                     __builtin_amdgcn_sched_barrier(0); } while (0)
#define VMW(n) asm volatile("s_waitcnt vmcnt(" #n ")" ::: "memory")

// A-half qm: 8 ds_read_b128 -> af[j][ks]
#define LOADA(buf, qm) do { \
  const char* _b = (const char*)&As[buf][qm][0]; \
  _Pragma("unroll") \
  for (int j = 0; j < 4; ++j) { \
    const int _lr = (2 * j + wm) * 16 + fr; \
    af[j][0] = *(const f16x8*)(_b + _lr * 128 + (((qk    ) ^ x7) << 4)); \
    af[j][1] = *(const f16x8*)(_b + _lr * 128 + (((qk + 4) ^ x7) << 4)); \
  } } while (0)

// B-half qn: 4 ds_read_b128 -> bf[nl][ks]
#define LOADB(buf, qn, bf) do { \
  const char* _b = (const char*)&Bs[buf][qn][0]; \
  _Pragma("unroll") \
  for (int nl = 0; nl < 2; ++nl) { \
    const int _lr = nl * 64 + wn * 16 + fr; \
    bf[nl][0] = *(const f16x8*)(_b + _lr * 128 + (((qk    ) ^ x7) << 4)); \
    bf[nl][1] = *(const f16x8*)(_b + _lr * 128 + (((qk + 4) ^ x7) << 4)); \
  } } while (0)

// 16 MFMA for quadrant (qm, qn)
#define MFMAQ(qm, qn, bf) do { \
  __builtin_amdgcn_s_setprio(1); \
  _Pragma("unroll") \
  for (int j = 0; j < 4; ++j) \
    _Pragma("unroll") \
    for (int nl = 0; nl < 2; ++nl) { \
      acc[(qm)*4 + j][(qn)*2 + nl] = __builtin_amdgcn_mfma_f32_16x16x32_f16( \
          af[j][0], bf[nl][0], acc[(qm)*4 + j][(qn)*2 + nl], 0, 0, 0); \
      acc[(qm)*4 + j][(qn)*2 + nl] = __builtin_amdgcn_mfma_f32_16x16x32_f16( \
          af[j][1], bf[nl][1], acc[(qm)*4 + j][(qn)*2 + nl], 0, 0, 0); \
    } \
  __builtin_amdgcn_s_setprio(0); } while (0)

// stage one 128x64 f16 half-tile: 2 x global_load_lds(16B), linear LDS dest,
// inverse-swizzled global source (slot^(row&7)) so swizzled reads see logical data
#define STAGE(dstHalf, srcPanel, h, ktn) do { \
  _Pragma("unroll") \
  for (int _i = 0; _i < 2; ++_i) { \
    const f16* _g = (srcPanel) + (size_t)((h) * 128 + _i * 64 + st_row) * K_DIM \
                    + (ktn) * 64 + st_slot * 8; \
    char* _l = (char*)(dstHalf) + _i * 8192 + wid * 1024; \
    __builtin_amdgcn_global_load_lds( \
        (const __attribute__((address_space(1))) void*)_g, \
        (__attribute__((address_space(3))) void*)_l, 16, 0, 0); \
  } } while (0)

__global__ __launch_bounds__(512) void w8a16_gemm_f16_kernel(
    const f16* __restrict__ Af,   // [M][K]
    const f16* __restrict__ Wf,   // [N][K], scale folded
    float* __restrict__ Out)      // [M][N]
{
  // halves: [buf][half][128 rows][64 f16]; 16B slots XOR-swizzled by (row&7)
  __shared__ __align__(16) f16 As[2][2][128 * 64];
  __shared__ __align__(16) f16 Bs[2][2][128 * 64];

  const int t    = threadIdx.x;
  const int lane = t & 63;
  const int wid  = t >> 6;       // 0..7
  const int wm   = wid >> 2;     // 0..1  (M row-tile interleave)
  const int wn   = wid & 3;      // 0..3  (N col-tile interleave)
  const int fr   = lane & 15;
  const int qk   = lane >> 4;    // k-quarter
  const int x7   = fr & 7;       // read-side XOR (row&7 == fr&7 here)

  // staging thread map: st_row 0..63 within 64-row issue, slot pre-swizzled
  const int st_row  = t >> 3;
  const int st_slot = (t & 7) ^ ((t >> 3) & 7);

  // XCD swizzle: 512 blocks, %8==0 -> simple bijective form
  const int bid = blockIdx.x;
  const int swz = (bid & 7) * 64 + (bid >> 3);
  const int tn  = swz & 15;      // 16 N-tiles
  const int tm  = swz >> 4;      // 32 M-tiles

  const f16* aSrc = Af + (size_t)tm * BM * K_DIM;
  const f16* bSrc = Wf + (size_t)tn * BN * K_DIM;

  f32x4 acc[8][4] = {};
  f16x8 af[4][2], bf0[2][2], bf1[2][2];

  // prologue: stage K-tile 0 (HA0,HB0,HB1,HA1); confirm first 3 halves
  STAGE(&As[0][0][0], aSrc, 0, 0);
  STAGE(&Bs[0][0][0], bSrc, 0, 0);
  STAGE(&Bs[0][1][0], bSrc, 1, 0);
  STAGE(&As[0][1][0], aSrc, 1, 0);
  VMW(2);
  BARX();

  for (int kt = 0; kt < NKT; ++kt) {
    const int  buf  = kt & 1;
    const int  nbuf = buf ^ 1;
    const bool more = (kt + 1) < NKT;

    // ---- p1: quadrant (A0,B0); stage HA0(kt+1)
    LOADA(buf, 0);
    LOADB(buf, 0, bf0);
    if (more) STAGE(&As[nbuf][0][0], aSrc, 0, kt + 1);
    BARX(); LGKM0();
    MFMAQ(0, 0, bf0);
    BARX();

    // ---- p2: quadrant (A0,B1); stage HB0(kt+1); counted wait
    LOADB(buf, 1, bf1);
    if (more) { STAGE(&Bs[nbuf][0][0], bSrc, 0, kt + 1); VMW(4); }
    else      { VMW(0); }
    BARX(); LGKM0();
    MFMAQ(0, 1, bf1);
    BARX();

    // ---- p3: quadrant (A1,B1); stage HB1(kt+1)
    LOADA(buf, 1);
    if (more) STAGE(&Bs[nbuf][1][0], bSrc, 1, kt + 1);
    BARX(); LGKM0();
    MFMAQ(1, 1, bf1);
    BARX();

    // ---- p4: quadrant (A1,B0) (bf0 reg-reuse); stage HA1(kt+1); counted wait
    if (more) { STAGE(&As[nbuf][1][0], aSrc, 1, kt + 1); VMW(2); }
    BARX(); LGKM0();
    MFMAQ(1, 0, bf0);
    BARX();
  }

  // epilogue: C/D col = lane&15, row = (lane>>4)*4 + reg
  const int fq = lane >> 4;
  #pragma unroll
  for (int mi = 0; mi < 8; ++mi) {
    const size_t row = (size_t)tm * BM + (mi * 2 + wm) * 16 + fq * 4;
    #pragma unroll
    for (int ni = 0; ni < 4; ++ni) {
      const size_t col = (size_t)tn * BN + ni * 64 + wn * 16 + fr;
      #pragma unroll
      for (int r = 0; r < 4; ++r)
        Out[(row + r) * N_DIM + col] = acc[mi][ni][r];
    }
  }
}

// ---------------- fallback (round-3 verified path) ----------------

__global__ __launch_bounds__(256) void w8a16_gemm_fb_kernel(
    const float* __restrict__ A, const int* __restrict__ Qw,
    const float* __restrict__ Sc, float* __restrict__ Out)
{
  __shared__ __align__(16) float Asf[2][128 * 32];
  __shared__ __align__(16) f16 Bsf[2][128][32];

  const int t = threadIdx.x, lane = t & 63, wid = t >> 6;
  const int wr = wid >> 1, wc = wid & 1;
  const int nwg = gridDim.x, cpx = nwg >> 3, bid = blockIdx.x;
  const int swz = (bid & 7) * cpx + (bid >> 3);
  const int tn = swz & 31, tm = swz >> 5;
  const size_t a_base = (size_t)tm * 128 * K_DIM;
  const size_t b_base = (size_t)tn * 128 * K_DIM;
  f32x4 acc[4][4] = {};
  const int a_r = t >> 3;
  const int a_slog = (t & 7) ^ ((t >> 3) & 7);

  auto stageA = [&](int buf, int kt) {
    #pragma unroll
    for (int c = 0; c < 4; ++c) {
      const float* g = A + a_base + (size_t)(c * 32 + a_r) * K_DIM + kt * 32 + a_slog * 4;
      char* l = (char*)&Asf[buf][0] + c * 4096 + wid * 1024;
      __builtin_amdgcn_global_load_lds(
          (const __attribute__((address_space(1))) void*)g,
          (__attribute__((address_space(3))) void*)l, 16, 0, 0);
    }
  };
  const int b_r = t >> 3, b_col = (t & 7) * 4;
  auto loadB = [&](int kt, int4* v) {
    #pragma unroll
    for (int c = 0; c < 4; ++c)
      v[c] = *(const int4*)(Qw + b_base + (size_t)(c * 32 + b_r) * K_DIM + kt * 32 + b_col);
  };
  auto writeB = [&](int buf, const int4* v) {
    #pragma unroll
    for (int c = 0; c < 4; ++c) {
      f16x2 lo = cvt2((float)v[c].x, (float)v[c].y);
      f16x2 hi = cvt2((float)v[c].z, (float)v[c].w);
      *(f16x2*)&Bsf[buf][c * 32 + b_r][b_col] = lo;
      *(f16x2*)&Bsf[buf][c * 32 + b_r][b_col + 2] = hi;
    }
  };
  auto compute = [&](int buf) {
    const int fr2 = lane & 15, q = lane >> 4;
    f16x8 af2[4], bf2[4];
    #pragma unroll
    for (int i = 0; i < 4; ++i) {
      const int r = wr * 64 + i * 16 + fr2;
      const float* base = &Asf[buf][0] + r * 32;
      const int s0 = q * 2;
      f32x4 a0 = *(const f32x4*)(base + ((s0 ^ (r & 7)) * 4));
      f32x4 a1 = *(const f32x4*)(base + (((s0 + 1) ^ (r & 7)) * 4));
      f16x2 p0 = cvt2(a0.x, a0.y), p1 = cvt2(a0.z, a0.w);
      f16x2 p2 = cvt2(a1.x, a1.y), p3 = cvt2(a1.z, a1.w);
      af2[i] = (f16x8){p0.x, p0.y, p1.x, p1.y, p2.x, p2.y, p3.x, p3.y};
      bf2[i] = *(const f16x8*)&Bsf[buf][wc * 64 + i * 16 + fr2][q * 8];
    }
    #pragma unroll
    for (int mi = 0; mi < 4; ++mi)
      #pragma unroll
      for (int ni = 0; ni < 4; ++ni)
        acc[mi][ni] = __builtin_amdgcn_mfma_f32_16x16x32_f16(
            af2[mi], bf2[ni], acc[mi][ni], 0, 0, 0);
  };

  { int4 b0[4]; stageA(0, 0); loadB(0, b0); writeB(0, b0); }
  __syncthreads();
  for (int kt = 0; kt < K_DIM / 32; ++kt) {
    const int buf = kt & 1;
    const bool more = (kt + 1) < K_DIM / 32;
    int4 nb[4];
    if (more) { stageA(buf ^ 1, kt + 1); loadB(kt + 1, nb); }
    compute(buf);
    if (more) writeB(buf ^ 1, nb);
    __syncthreads();
  }
  const int fr2 = lane & 15, fq = lane >> 4;
  const int cb = tn * 128 + wc * 64 + fr2;
  const int rb = tm * 128 + wr * 64 + fq * 4;
  #pragma unroll
  for (int ni = 0; ni < 4; ++ni) {
    const float s = Sc[cb + ni * 16];
    #pragma unroll
    for (int mi = 0; mi < 4; ++mi)
      #pragma unroll
      for (int r = 0; r < 4; ++r)
        Out[(size_t)(rb + mi * 16 + r) * N_DIM + (cb + ni * 16)] =
            acc[mi][ni][r] * s;
  }
}

extern "C" void kernel_launch(void* const* d_in, const int* in_sizes, int n_in,
                              void* d_out, int out_size, void* d_ws, size_t ws_size,
                              hipStream_t stream) {
  const float* A  = (const float*)d_in[0];
  const int*   Qw = (const int*)d_in[1];
  const float* Sc = (const float*)d_in[2];
  float*       Out = (float*)d_out;

  const size_t a_bytes = (size_t)M_DIM * K_DIM * sizeof(f16);  // 64 MB
  const size_t w_bytes = (size_t)N_DIM * K_DIM * sizeof(f16);  // 32 MB

  if (ws_size >= a_bytes + w_bytes) {
    f16* Af = (f16*)d_ws;
    f16* Wf = (f16*)((char*)d_ws + a_bytes);
    conv_a_kernel<<<2048, 256, 0, stream>>>(A, Af);
    conv_b_kernel<<<N_DIM, 256, 0, stream>>>(Qw, Sc, Wf);
    dim3 grid((M_DIM / BM) * (N_DIM / BN));  // 32*16 = 512
    w8a16_gemm_f16_kernel<<<grid, 512, 0, stream>>>(Af, Wf, Out);
  } else {
    dim3 grid((M_DIM / 128) * (N_DIM / 128));
    w8a16_gemm_fb_kernel<<<grid, 256, 0, stream>>>(A, Qw, Sc, Out);
  }
}

// Round 6
// 289.492 us; speedup vs baseline: 2.1183x; 1.0551x over previous
//
#include <hip/hip_runtime.h>
#include <stdint.h>

// W8A16 quantized linear, two-phase:
//   Pre-pass: A f32->f16 (64 MB), W = fp16(q*scale) (32 MB) into d_ws.
//   GEMM:     256x256 tile, BK=64, 8 waves (2M x 4N), 4-phase/K-tile schedule
//             with counted vmcnt, raw s_barrier, setprio MFMA clusters,
//             XOR-swizzled LDS (T2, verified 0 conflicts in R5), both
//             operands via global_load_lds width=16.
// Schedule ledger (per wave; HX' = half-tile of kt+1, 2 vm-insts each).
// Issues: p1: HA0'+HB0'; p2: HB1'; p3: HA1'; p4: none.
// Waits:  p1: vmcnt(6) retires HB1(kt)  [issued p2(kt-1), slack 3 phases]
//         p2: vmcnt(6) retires HA1(kt)  [issued p3(kt-1), slack 3]
//         p4: vmcnt(4) retires HA0',HB0' [issued p1(kt), slack 3]
// Invariant entering p1: outstanding = [HB1(kt), HA1(kt)] = 4.
// Reads: p1 {A0,B0}, p2 {B1}, p3 {A1}, p4 reg-reuse; every wait is sealed by
// a barrier before the dependent ds_reads. Tail: vmcnt(2)/vmcnt(0).

#define M_DIM 8192
#define N_DIM 4096
#define K_DIM 4096
#define BM 256
#define BN 256
#define BK 64
#define NKT (K_DIM / BK)   // 64 K-tiles

typedef _Float16 f16;
typedef f16 f16x8 __attribute__((ext_vector_type(8)));
typedef f16 f16x2 __attribute__((ext_vector_type(2)));
typedef float f32x4 __attribute__((ext_vector_type(4)));

static __device__ __forceinline__ f16x2 cvt2(float a, float b) {
  return __builtin_bit_cast(f16x2, __builtin_amdgcn_cvt_pkrtz(a, b));
}

// ---------------- pre-pass kernels ----------------

__global__ __launch_bounds__(256) void conv_a_kernel(
    const float* __restrict__ A, f16* __restrict__ Af)
{
  const size_t stride = (size_t)gridDim.x * blockDim.x;
  size_t i = (size_t)blockIdx.x * blockDim.x + threadIdx.x;
  const size_t n8 = (size_t)M_DIM * K_DIM / 8;
  for (; i < n8; i += stride) {
    const f32x4* p = (const f32x4*)(A + i * 8);
    f32x4 v0 = p[0], v1 = p[1];
    f16x2 a = cvt2(v0.x, v0.y), b = cvt2(v0.z, v0.w);
    f16x2 c = cvt2(v1.x, v1.y), d = cvt2(v1.z, v1.w);
    *(f16x8*)(Af + i * 8) = (f16x8){a.x, a.y, b.x, b.y, c.x, c.y, d.x, d.y};
  }
}

__global__ __launch_bounds__(256) void conv_b_kernel(
    const int* __restrict__ Qw, const float* __restrict__ Sc,
    f16* __restrict__ Wf)
{
  const int o = blockIdx.x;
  const int t = threadIdx.x;
  const float s = Sc[o];
  const int* q = Qw + (size_t)o * K_DIM + t * 16;
  f16* w = Wf + (size_t)o * K_DIM + t * 16;
  #pragma unroll
  for (int h = 0; h < 2; ++h) {
    int4 u0 = *(const int4*)(q + h * 8);
    int4 u1 = *(const int4*)(q + h * 8 + 4);
    f16x2 a = cvt2((float)u0.x * s, (float)u0.y * s);
    f16x2 b = cvt2((float)u0.z * s, (float)u0.w * s);
    f16x2 c = cvt2((float)u1.x * s, (float)u1.y * s);
    f16x2 d = cvt2((float)u1.z * s, (float)u1.w * s);
    *(f16x8*)(w + h * 8) = (f16x8){a.x, a.y, b.x, b.y, c.x, c.y, d.x, d.y};
  }
}

// ---------------- main GEMM: 256^2, BK=64, 8 waves, phase-split ----------------

#define BARX() __builtin_amdgcn_s_barrier()
#define LGKM0() do { asm volatile("s_waitcnt lgkmcnt(0)" ::: "memory"); \
                     __builtin_amdgcn_sched_barrier(0); } while (0)
#define VMW(n) asm volatile("s_waitcnt vmcnt(" #n ")" ::: "memory")

// A-half qm: 8 ds_read_b128 -> af[j][ks]
#define LOADA(buf, qm) do { \
  const char* _b = (const char*)&As[buf][qm][0]; \
  _Pragma("unroll") \
  for (int j = 0; j < 4; ++j) { \
    const int _lr = (2 * j + wm) * 16 + fr; \
    af[j][0] = *(const f16x8*)(_b + _lr * 128 + (((qk    ) ^ x7) << 4)); \
    af[j][1] = *(const f16x8*)(_b + _lr * 128 + (((qk + 4) ^ x7) << 4)); \
  } } while (0)

// B-half qn: 4 ds_read_b128 -> bf[nl][ks]
#define LOADB(buf, qn, bf) do { \
  const char* _b = (const char*)&Bs[buf][qn][0]; \
  _Pragma("unroll") \
  for (int nl = 0; nl < 2; ++nl) { \
    const int _lr = nl * 64 + wn * 16 + fr; \
    bf[nl][0] = *(const f16x8*)(_b + _lr * 128 + (((qk    ) ^ x7) << 4)); \
    bf[nl][1] = *(const f16x8*)(_b + _lr * 128 + (((qk + 4) ^ x7) << 4)); \
  } } while (0)

// 16 MFMA for quadrant (qm, qn)
#define MFMAQ(qm, qn, bf) do { \
  __builtin_amdgcn_s_setprio(1); \
  _Pragma("unroll") \
  for (int j = 0; j < 4; ++j) \
    _Pragma("unroll") \
    for (int nl = 0; nl < 2; ++nl) { \
      acc[(qm)*4 + j][(qn)*2 + nl] = __builtin_amdgcn_mfma_f32_16x16x32_f16( \
          af[j][0], bf[nl][0], acc[(qm)*4 + j][(qn)*2 + nl], 0, 0, 0); \
      acc[(qm)*4 + j][(qn)*2 + nl] = __builtin_amdgcn_mfma_f32_16x16x32_f16( \
          af[j][1], bf[nl][1], acc[(qm)*4 + j][(qn)*2 + nl], 0, 0, 0); \
    } \
  __builtin_amdgcn_s_setprio(0); } while (0)

// stage one 128x64 f16 half-tile: 2 x global_load_lds(16B), linear LDS dest,
// inverse-swizzled global source (slot^(row&7)) so swizzled reads see logical data
#define STAGE(dstHalf, srcPanel, h, ktn) do { \
  _Pragma("unroll") \
  for (int _i = 0; _i < 2; ++_i) { \
    const f16* _g = (srcPanel) + (size_t)((h) * 128 + _i * 64 + st_row) * K_DIM \
                    + (ktn) * 64 + st_slot * 8; \
    char* _l = (char*)(dstHalf) + _i * 8192 + wid * 1024; \
    __builtin_amdgcn_global_load_lds( \
        (const __attribute__((address_space(1))) void*)_g, \
        (__attribute__((address_space(3))) void*)_l, 16, 0, 0); \
  } } while (0)

__global__ __launch_bounds__(512) void w8a16_gemm_f16_kernel(
    const f16* __restrict__ Af,   // [M][K]
    const f16* __restrict__ Wf,   // [N][K], scale folded
    float* __restrict__ Out)      // [M][N]
{
  // halves: [buf][half][128 rows][64 f16]; 16B slots XOR-swizzled by (row&7)
  __shared__ __align__(16) f16 As[2][2][128 * 64];
  __shared__ __align__(16) f16 Bs[2][2][128 * 64];

  const int t    = threadIdx.x;
  const int lane = t & 63;
  const int wid  = t >> 6;       // 0..7
  const int wm   = wid >> 2;     // 0..1  (M row-tile interleave)
  const int wn   = wid & 3;      // 0..3  (N col-tile interleave)
  const int fr   = lane & 15;
  const int qk   = lane >> 4;    // k-quarter
  const int x7   = fr & 7;       // read-side XOR (row&7 == fr&7 here)

  // staging thread map: st_row 0..63 within 64-row issue, slot pre-swizzled
  const int st_row  = t >> 3;
  const int st_slot = (t & 7) ^ ((t >> 3) & 7);

  // XCD swizzle: 512 blocks, %8==0 -> simple bijective form
  const int bid = blockIdx.x;
  const int swz = (bid & 7) * 64 + (bid >> 3);
  const int tn  = swz & 15;      // 16 N-tiles
  const int tm  = swz >> 4;      // 32 M-tiles

  const f16* aSrc = Af + (size_t)tm * BM * K_DIM;
  const f16* bSrc = Wf + (size_t)tn * BN * K_DIM;

  f32x4 acc[8][4] = {};
  f16x8 af[4][2], bf0[2][2], bf1[2][2];

  // prologue: stage K-tile 0 (HA0,HB0,HB1,HA1); confirm HA0,HB0 ->
  // invariant entering p1(0): outstanding = [HB1(0), HA1(0)] = 4
  STAGE(&As[0][0][0], aSrc, 0, 0);
  STAGE(&Bs[0][0][0], bSrc, 0, 0);
  STAGE(&Bs[0][1][0], bSrc, 1, 0);
  STAGE(&As[0][1][0], aSrc, 1, 0);
  VMW(4);
  BARX();

  for (int kt = 0; kt < NKT; ++kt) {
    const int  buf  = kt & 1;
    const int  nbuf = buf ^ 1;
    const bool more = (kt + 1) < NKT;

    // ---- p1: quadrant (A0,B0); issue HA0',HB0'; retire HB1(kt)
    LOADA(buf, 0);
    LOADB(buf, 0, bf0);
    if (more) {
      STAGE(&As[nbuf][0][0], aSrc, 0, kt + 1);
      STAGE(&Bs[nbuf][0][0], bSrc, 0, kt + 1);
      VMW(6);
    } else VMW(2);
    BARX(); LGKM0();
    MFMAQ(0, 0, bf0);
    BARX();

    // ---- p2: quadrant (A0,B1); issue HB1'; retire HA1(kt)
    LOADB(buf, 1, bf1);
    if (more) {
      STAGE(&Bs[nbuf][1][0], bSrc, 1, kt + 1);
      VMW(6);
    } else VMW(0);
    BARX(); LGKM0();
    MFMAQ(0, 1, bf1);
    BARX();

    // ---- p3: quadrant (A1,B1); issue HA1'; no wait
    LOADA(buf, 1);
    if (more) STAGE(&As[nbuf][1][0], aSrc, 1, kt + 1);
    BARX(); LGKM0();
    MFMAQ(1, 1, bf1);
    BARX();

    // ---- p4: quadrant (A1,B0) (bf0 reg-reuse); retire HA0',HB0'
    if (more) VMW(4);
    BARX(); LGKM0();
    MFMAQ(1, 0, bf0);
    BARX();
  }

  // epilogue: C/D col = lane&15, row = (lane>>4)*4 + reg
  const int fq = lane >> 4;
  #pragma unroll
  for (int mi = 0; mi < 8; ++mi) {
    const size_t row = (size_t)tm * BM + (mi * 2 + wm) * 16 + fq * 4;
    #pragma unroll
    for (int ni = 0; ni < 4; ++ni) {
      const size_t col = (size_t)tn * BN + ni * 64 + wn * 16 + fr;
      #pragma unroll
      for (int r = 0; r < 4; ++r)
        Out[(row + r) * N_DIM + col] = acc[mi][ni][r];
    }
  }
}

// ---------------- fallback (round-3 verified path) ----------------

__global__ __launch_bounds__(256) void w8a16_gemm_fb_kernel(
    const float* __restrict__ A, const int* __restrict__ Qw,
    const float* __restrict__ Sc, float* __restrict__ Out)
{
  __shared__ __align__(16) float Asf[2][128 * 32];
  __shared__ __align__(16) f16 Bsf[2][128][32];

  const int t = threadIdx.x, lane = t & 63, wid = t >> 6;
  const int wr = wid >> 1, wc = wid & 1;
  const int nwg = gridDim.x, cpx = nwg >> 3, bid = blockIdx.x;
  const int swz = (bid & 7) * cpx + (bid >> 3);
  const int tn = swz & 31, tm = swz >> 5;
  const size_t a_base = (size_t)tm * 128 * K_DIM;
  const size_t b_base = (size_t)tn * 128 * K_DIM;
  f32x4 acc[4][4] = {};
  const int a_r = t >> 3;
  const int a_slog = (t & 7) ^ ((t >> 3) & 7);

  auto stageA = [&](int buf, int kt) {
    #pragma unroll
    for (int c = 0; c < 4; ++c) {
      const float* g = A + a_base + (size_t)(c * 32 + a_r) * K_DIM + kt * 32 + a_slog * 4;
      char* l = (char*)&Asf[buf][0] + c * 4096 + wid * 1024;
      __builtin_amdgcn_global_load_lds(
          (const __attribute__((address_space(1))) void*)g,
          (__attribute__((address_space(3))) void*)l, 16, 0, 0);
    }
  };
  const int b_r = t >> 3, b_col = (t & 7) * 4;
  auto loadB = [&](int kt, int4* v) {
    #pragma unroll
    for (int c = 0; c < 4; ++c)
      v[c] = *(const int4*)(Qw + b_base + (size_t)(c * 32 + b_r) * K_DIM + kt * 32 + b_col);
  };
  auto writeB = [&](int buf, const int4* v) {
    #pragma unroll
    for (int c = 0; c < 4; ++c) {
      f16x2 lo = cvt2((float)v[c].x, (float)v[c].y);
      f16x2 hi = cvt2((float)v[c].z, (float)v[c].w);
      *(f16x2*)&Bsf[buf][c * 32 + b_r][b_col] = lo;
      *(f16x2*)&Bsf[buf][c * 32 + b_r][b_col + 2] = hi;
    }
  };
  auto compute = [&](int buf) {
    const int fr2 = lane & 15, q = lane >> 4;
    f16x8 af2[4], bf2[4];
    #pragma unroll
    for (int i = 0; i < 4; ++i) {
      const int r = wr * 64 + i * 16 + fr2;
      const float* base = &Asf[buf][0] + r * 32;
      const int s0 = q * 2;
      f32x4 a0 = *(const f32x4*)(base + ((s0 ^ (r & 7)) * 4));
      f32x4 a1 = *(const f32x4*)(base + (((s0 + 1) ^ (r & 7)) * 4));
      f16x2 p0 = cvt2(a0.x, a0.y), p1 = cvt2(a0.z, a0.w);
      f16x2 p2 = cvt2(a1.x, a1.y), p3 = cvt2(a1.z, a1.w);
      af2[i] = (f16x8){p0.x, p0.y, p1.x, p1.y, p2.x, p2.y, p3.x, p3.y};
      bf2[i] = *(const f16x8*)&Bsf[buf][wc * 64 + i * 16 + fr2][q * 8];
    }
    #pragma unroll
    for (int mi = 0; mi < 4; ++mi)
      #pragma unroll
      for (int ni = 0; ni < 4; ++ni)
        acc[mi][ni] = __builtin_amdgcn_mfma_f32_16x16x32_f16(
            af2[mi], bf2[ni], acc[mi][ni], 0, 0, 0);
  };

  { int4 b0[4]; stageA(0, 0); loadB(0, b0); writeB(0, b0); }
  __syncthreads();
  for (int kt = 0; kt < K_DIM / 32; ++kt) {
    const int buf = kt & 1;
    const bool more = (kt + 1) < K_DIM / 32;
    int4 nb[4];
    if (more) { stageA(buf ^ 1, kt + 1); loadB(kt + 1, nb); }
    compute(buf);
    if (more) writeB(buf ^ 1, nb);
    __syncthreads();
  }
  const int fr2 = lane & 15, fq = lane >> 4;
  const int cb = tn * 128 + wc * 64 + fr2;
  const int rb = tm * 128 + wr * 64 + fq * 4;
  #pragma unroll
  for (int ni = 0; ni < 4; ++ni) {
    const float s = Sc[cb + ni * 16];
    #pragma unroll
    for (int mi = 0; mi < 4; ++mi)
      #pragma unroll
      for (int r = 0; r < 4; ++r)
        Out[(size_t)(rb + mi * 16 + r) * N_DIM + (cb + ni * 16)] =
            acc[mi][ni][r] * s;
  }
}

extern "C" void kernel_launch(void* const* d_in, const int* in_sizes, int n_in,
                              void* d_out, int out_size, void* d_ws, size_t ws_size,
                              hipStream_t stream) {
  const float* A  = (const float*)d_in[0];
  const int*   Qw = (const int*)d_in[1];
  const float* Sc = (const float*)d_in[2];
  float*       Out = (float*)d_out;

  const size_t a_bytes = (size_t)M_DIM * K_DIM * sizeof(f16);  // 64 MB
  const size_t w_bytes = (size_t)N_DIM * K_DIM * sizeof(f16);  // 32 MB

  if (ws_size >= a_bytes + w_bytes) {
    f16* Af = (f16*)d_ws;
    f16* Wf = (f16*)((char*)d_ws + a_bytes);
    conv_a_kernel<<<2048, 256, 0, stream>>>(A, Af);
    conv_b_kernel<<<N_DIM, 256, 0, stream>>>(Qw, Sc, Wf);
    dim3 grid((M_DIM / BM) * (N_DIM / BN));  // 32*16 = 512
    w8a16_gemm_f16_kernel<<<grid, 512, 0, stream>>>(Af, Wf, Out);
  } else {
    dim3 grid((M_DIM / 128) * (N_DIM / 128));
    w8a16_gemm_fb_kernel<<<grid, 256, 0, stream>>>(A, Qw, Sc, Out);
  }
}

// Round 7
// 286.612 us; speedup vs baseline: 2.1396x; 1.0100x over previous
//
#include <hip/hip_runtime.h>
#include <stdint.h>

// W8A16 quantized linear, two-phase:
//   Pre-pass: A f32->f16 (64 MB), W = fp16(q*scale) (32 MB) into d_ws.
//   GEMM:     256x256 tile, BK=64, 8 waves (2M x 4N), ONE barrier pair per
//             K-tile; interior unwalled (compiler schedules ds_read/MFMA
//             overlap with its own counted lgkmcnt). Stages for kt+1 issued
//             at tile top (full-tile slack), confirmed by vmcnt(0)+barrier
//             at tile end. T2 XOR-swizzled LDS (0 conflicts, verified R5/R6).
// Race ledger:
//   - reads of buf(kt) covered by tile-start barrier (stages of kt confirmed
//     at the kt-1/kt boundary: per-wave vmcnt(0) + s_barrier = block-wide).
//   - all 24 ds_reads of a tile complete before its last MFMA issues
//     (compiler dependence waits, in-order DS completion), so by the
//     boundary barrier no wave still reads the buffer that kt+1 overwrites.
//   - last tile peeled: no staging, no vmcnt needed.

#define M_DIM 8192
#define N_DIM 4096
#define K_DIM 4096
#define BM 256
#define BN 256
#define BK 64
#define NKT (K_DIM / BK)   // 64 K-tiles

typedef _Float16 f16;
typedef f16 f16x8 __attribute__((ext_vector_type(8)));
typedef f16 f16x2 __attribute__((ext_vector_type(2)));
typedef float f32x4 __attribute__((ext_vector_type(4)));

static __device__ __forceinline__ f16x2 cvt2(float a, float b) {
  return __builtin_bit_cast(f16x2, __builtin_amdgcn_cvt_pkrtz(a, b));
}

// ---------------- pre-pass kernels ----------------

__global__ __launch_bounds__(256) void conv_a_kernel(
    const float* __restrict__ A, f16* __restrict__ Af)
{
  const size_t stride = (size_t)gridDim.x * blockDim.x;
  size_t i = (size_t)blockIdx.x * blockDim.x + threadIdx.x;
  const size_t n8 = (size_t)M_DIM * K_DIM / 8;
  for (; i < n8; i += stride) {
    const f32x4* p = (const f32x4*)(A + i * 8);
    f32x4 v0 = p[0], v1 = p[1];
    f16x2 a = cvt2(v0.x, v0.y), b = cvt2(v0.z, v0.w);
    f16x2 c = cvt2(v1.x, v1.y), d = cvt2(v1.z, v1.w);
    *(f16x8*)(Af + i * 8) = (f16x8){a.x, a.y, b.x, b.y, c.x, c.y, d.x, d.y};
  }
}

__global__ __launch_bounds__(256) void conv_b_kernel(
    const int* __restrict__ Qw, const float* __restrict__ Sc,
    f16* __restrict__ Wf)
{
  const int o = blockIdx.x;
  const int t = threadIdx.x;
  const float s = Sc[o];
  const int* q = Qw + (size_t)o * K_DIM + t * 16;
  f16* w = Wf + (size_t)o * K_DIM + t * 16;
  #pragma unroll
  for (int h = 0; h < 2; ++h) {
    int4 u0 = *(const int4*)(q + h * 8);
    int4 u1 = *(const int4*)(q + h * 8 + 4);
    f16x2 a = cvt2((float)u0.x * s, (float)u0.y * s);
    f16x2 b = cvt2((float)u0.z * s, (float)u0.w * s);
    f16x2 c = cvt2((float)u1.x * s, (float)u1.y * s);
    f16x2 d = cvt2((float)u1.z * s, (float)u1.w * s);
    *(f16x8*)(w + h * 8) = (f16x8){a.x, a.y, b.x, b.y, c.x, c.y, d.x, d.y};
  }
}

// ---------------- main GEMM: 256^2, BK=64, 8 waves ----------------

#define BARX() __builtin_amdgcn_s_barrier()
#define SCHED0() __builtin_amdgcn_sched_barrier(0)
#define VMW0() asm volatile("s_waitcnt vmcnt(0)" ::: "memory")

// A-half qm: 8 ds_read_b128 -> af[j][ks]
#define LOADA(buf, qm) do { \
  const char* _b = (const char*)&As[buf][qm][0]; \
  _Pragma("unroll") \
  for (int j = 0; j < 4; ++j) { \
    const int _lr = (2 * j + wm) * 16 + fr; \
    af[j][0] = *(const f16x8*)(_b + _lr * 128 + (((qk    ) ^ x7) << 4)); \
    af[j][1] = *(const f16x8*)(_b + _lr * 128 + (((qk + 4) ^ x7) << 4)); \
  } } while (0)

// B-half qn: 4 ds_read_b128 -> bf[nl][ks]
#define LOADB(buf, qn, bf) do { \
  const char* _b = (const char*)&Bs[buf][qn][0]; \
  _Pragma("unroll") \
  for (int nl = 0; nl < 2; ++nl) { \
    const int _lr = nl * 64 + wn * 16 + fr; \
    bf[nl][0] = *(const f16x8*)(_b + _lr * 128 + (((qk    ) ^ x7) << 4)); \
    bf[nl][1] = *(const f16x8*)(_b + _lr * 128 + (((qk + 4) ^ x7) << 4)); \
  } } while (0)

// 16 MFMA for quadrant (qm, qn)
#define MFMAQ(qm, qn, bf) do { \
  __builtin_amdgcn_s_setprio(1); \
  _Pragma("unroll") \
  for (int j = 0; j < 4; ++j) \
    _Pragma("unroll") \
    for (int nl = 0; nl < 2; ++nl) { \
      acc[(qm)*4 + j][(qn)*2 + nl] = __builtin_amdgcn_mfma_f32_16x16x32_f16( \
          af[j][0], bf[nl][0], acc[(qm)*4 + j][(qn)*2 + nl], 0, 0, 0); \
      acc[(qm)*4 + j][(qn)*2 + nl] = __builtin_amdgcn_mfma_f32_16x16x32_f16( \
          af[j][1], bf[nl][1], acc[(qm)*4 + j][(qn)*2 + nl], 0, 0, 0); \
    } \
  __builtin_amdgcn_s_setprio(0); } while (0)

// stage one 128x64 f16 half-tile: 2 x global_load_lds(16B), linear LDS dest,
// inverse-swizzled global source (slot^(row&7))
#define STAGE(dstHalf, srcPanel, h, ktn) do { \
  _Pragma("unroll") \
  for (int _i = 0; _i < 2; ++_i) { \
    const f16* _g = (srcPanel) + (size_t)((h) * 128 + _i * 64 + st_row) * K_DIM \
                    + (ktn) * 64 + st_slot * 8; \
    char* _l = (char*)(dstHalf) + _i * 8192 + wid * 1024; \
    __builtin_amdgcn_global_load_lds( \
        (const __attribute__((address_space(1))) void*)_g, \
        (__attribute__((address_space(3))) void*)_l, 16, 0, 0); \
  } } while (0)

__global__ __launch_bounds__(512) void w8a16_gemm_f16_kernel(
    const f16* __restrict__ Af,   // [M][K]
    const f16* __restrict__ Wf,   // [N][K], scale folded
    float* __restrict__ Out)      // [M][N]
{
  // halves: [buf][half][128 rows][64 f16]; 16B slots XOR-swizzled by (row&7)
  __shared__ __align__(16) f16 As[2][2][128 * 64];
  __shared__ __align__(16) f16 Bs[2][2][128 * 64];

  const int t    = threadIdx.x;
  const int lane = t & 63;
  const int wid  = t >> 6;       // 0..7
  const int wm   = wid >> 2;     // 0..1
  const int wn   = wid & 3;      // 0..3
  const int fr   = lane & 15;
  const int qk   = lane >> 4;
  const int x7   = fr & 7;

  const int st_row  = t >> 3;
  const int st_slot = (t & 7) ^ ((t >> 3) & 7);

  // XCD swizzle: 512 blocks, %8==0 -> simple bijective form
  const int bid = blockIdx.x;
  const int swz = (bid & 7) * 64 + (bid >> 3);
  const int tn  = swz & 15;      // 16 N-tiles
  const int tm  = swz >> 4;      // 32 M-tiles

  const f16* aSrc = Af + (size_t)tm * BM * K_DIM;
  const f16* bSrc = Wf + (size_t)tn * BN * K_DIM;

  f32x4 acc[8][4] = {};
  f16x8 af[4][2], bf0[2][2], bf1[2][2];

  // prologue: stage K-tile 0 fully; seal
  STAGE(&As[0][0][0], aSrc, 0, 0);
  STAGE(&Bs[0][0][0], bSrc, 0, 0);
  STAGE(&Bs[0][1][0], bSrc, 1, 0);
  STAGE(&As[0][1][0], aSrc, 1, 0);
  VMW0();
  BARX();
  SCHED0();

  for (int kt = 0; kt < NKT - 1; ++kt) {
    const int buf  = kt & 1;
    const int nbuf = buf ^ 1;

    // front-load reads (A0, B0, B1) — compiler pipelines with MFMAs below
    LOADA(buf, 0);
    LOADB(buf, 0, bf0);
    LOADB(buf, 1, bf1);

    // stage all of kt+1 now: confirm is a full tile away (~2500 cyc slack)
    STAGE(&As[nbuf][0][0], aSrc, 0, kt + 1);
    STAGE(&Bs[nbuf][0][0], bSrc, 0, kt + 1);
    STAGE(&Bs[nbuf][1][0], bSrc, 1, kt + 1);
    STAGE(&As[nbuf][1][0], aSrc, 1, kt + 1);

    MFMAQ(0, 0, bf0);
    MFMAQ(0, 1, bf1);

    LOADA(buf, 1);   // mid-tile A1 reads into af (reg reuse; WAR via scoreboard)

    MFMAQ(1, 1, bf1);
    MFMAQ(1, 0, bf0);

    SCHED0();
    VMW0();          // stages issued at tile top: temporally free drain
    BARX();
    SCHED0();
  }

  { // peeled last tile: no staging
    const int buf = (NKT - 1) & 1;
    LOADA(buf, 0);
    LOADB(buf, 0, bf0);
    LOADB(buf, 1, bf1);
    MFMAQ(0, 0, bf0);
    MFMAQ(0, 1, bf1);
    LOADA(buf, 1);
    MFMAQ(1, 1, bf1);
    MFMAQ(1, 0, bf0);
  }

  // epilogue: C/D col = lane&15, row = (lane>>4)*4 + reg
  const int fq = lane >> 4;
  #pragma unroll
  for (int mi = 0; mi < 8; ++mi) {
    const size_t row = (size_t)tm * BM + (mi * 2 + wm) * 16 + fq * 4;
    #pragma unroll
    for (int ni = 0; ni < 4; ++ni) {
      const size_t col = (size_t)tn * BN + ni * 64 + wn * 16 + fr;
      #pragma unroll
      for (int r = 0; r < 4; ++r)
        Out[(row + r) * N_DIM + col] = acc[mi][ni][r];
    }
  }
}

// ---------------- fallback (round-3 verified path) ----------------

__global__ __launch_bounds__(256) void w8a16_gemm_fb_kernel(
    const float* __restrict__ A, const int* __restrict__ Qw,
    const float* __restrict__ Sc, float* __restrict__ Out)
{
  __shared__ __align__(16) float Asf[2][128 * 32];
  __shared__ __align__(16) f16 Bsf[2][128][32];

  const int t = threadIdx.x, lane = t & 63, wid = t >> 6;
  const int wr = wid >> 1, wc = wid & 1;
  const int nwg = gridDim.x, cpx = nwg >> 3, bid = blockIdx.x;
  const int swz = (bid & 7) * cpx + (bid >> 3);
  const int tn = swz & 31, tm = swz >> 5;
  const size_t a_base = (size_t)tm * 128 * K_DIM;
  const size_t b_base = (size_t)tn * 128 * K_DIM;
  f32x4 acc[4][4] = {};
  const int a_r = t >> 3;
  const int a_slog = (t & 7) ^ ((t >> 3) & 7);

  auto stageA = [&](int buf, int kt) {
    #pragma unroll
    for (int c = 0; c < 4; ++c) {
      const float* g = A + a_base + (size_t)(c * 32 + a_r) * K_DIM + kt * 32 + a_slog * 4;
      char* l = (char*)&Asf[buf][0] + c * 4096 + wid * 1024;
      __builtin_amdgcn_global_load_lds(
          (const __attribute__((address_space(1))) void*)g,
          (__attribute__((address_space(3))) void*)l, 16, 0, 0);
    }
  };
  const int b_r = t >> 3, b_col = (t & 7) * 4;
  auto loadB = [&](int kt, int4* v) {
    #pragma unroll
    for (int c = 0; c < 4; ++c)
      v[c] = *(const int4*)(Qw + b_base + (size_t)(c * 32 + b_r) * K_DIM + kt * 32 + b_col);
  };
  auto writeB = [&](int buf, const int4* v) {
    #pragma unroll
    for (int c = 0; c < 4; ++c) {
      f16x2 lo = cvt2((float)v[c].x, (float)v[c].y);
      f16x2 hi = cvt2((float)v[c].z, (float)v[c].w);
      *(f16x2*)&Bsf[buf][c * 32 + b_r][b_col] = lo;
      *(f16x2*)&Bsf[buf][c * 32 + b_r][b_col + 2] = hi;
    }
  };
  auto compute = [&](int buf) {
    const int fr2 = lane & 15, q = lane >> 4;
    f16x8 af2[4], bf2[4];
    #pragma unroll
    for (int i = 0; i < 4; ++i) {
      const int r = wr * 64 + i * 16 + fr2;
      const float* base = &Asf[buf][0] + r * 32;
      const int s0 = q * 2;
      f32x4 a0 = *(const f32x4*)(base + ((s0 ^ (r & 7)) * 4));
      f32x4 a1 = *(const f32x4*)(base + (((s0 + 1) ^ (r & 7)) * 4));
      f16x2 p0 = cvt2(a0.x, a0.y), p1 = cvt2(a0.z, a0.w);
      f16x2 p2 = cvt2(a1.x, a1.y), p3 = cvt2(a1.z, a1.w);
      af2[i] = (f16x8){p0.x, p0.y, p1.x, p1.y, p2.x, p2.y, p3.x, p3.y};
      bf2[i] = *(const f16x8*)&Bsf[buf][wc * 64 + i * 16 + fr2][q * 8];
    }
    #pragma unroll
    for (int mi = 0; mi < 4; ++mi)
      #pragma unroll
      for (int ni = 0; ni < 4; ++ni)
        acc[mi][ni] = __builtin_amdgcn_mfma_f32_16x16x32_f16(
            af2[mi], bf2[ni], acc[mi][ni], 0, 0, 0);
  };

  { int4 b0[4]; stageA(0, 0); loadB(0, b0); writeB(0, b0); }
  __syncthreads();
  for (int kt = 0; kt < K_DIM / 32; ++kt) {
    const int buf = kt & 1;
    const bool more = (kt + 1) < K_DIM / 32;
    int4 nb[4];
    if (more) { stageA(buf ^ 1, kt + 1); loadB(kt + 1, nb); }
    compute(buf);
    if (more) writeB(buf ^ 1, nb);
    __syncthreads();
  }
  const int fr2 = lane & 15, fq = lane >> 4;
  const int cb = tn * 128 + wc * 64 + fr2;
  const int rb = tm * 128 + wr * 64 + fq * 4;
  #pragma unroll
  for (int ni = 0; ni < 4; ++ni) {
    const float s = Sc[cb + ni * 16];
    #pragma unroll
    for (int mi = 0; mi < 4; ++mi)
      #pragma unroll
      for (int r = 0; r < 4; ++r)
        Out[(size_t)(rb + mi * 16 + r) * N_DIM + (cb + ni * 16)] =
            acc[mi][ni][r] * s;
  }
}

extern "C" void kernel_launch(void* const* d_in, const int* in_sizes, int n_in,
                              void* d_out, int out_size, void* d_ws, size_t ws_size,
                              hipStream_t stream) {
  const float* A  = (const float*)d_in[0];
  const int*   Qw = (const int*)d_in[1];
  const float* Sc = (const float*)d_in[2];
  float*       Out = (float*)d_out;

  const size_t a_bytes = (size_t)M_DIM * K_DIM * sizeof(f16);  // 64 MB
  const size_t w_bytes = (size_t)N_DIM * K_DIM * sizeof(f16);  // 32 MB

  if (ws_size >= a_bytes + w_bytes) {
    f16* Af = (f16*)d_ws;
    f16* Wf = (f16*)((char*)d_ws + a_bytes);
    conv_a_kernel<<<2048, 256, 0, stream>>>(A, Af);
    conv_b_kernel<<<N_DIM, 256, 0, stream>>>(Qw, Sc, Wf);
    dim3 grid((M_DIM / BM) * (N_DIM / BN));  // 32*16 = 512
    w8a16_gemm_f16_kernel<<<grid, 512, 0, stream>>>(Af, Wf, Out);
  } else {
    dim3 grid((M_DIM / 128) * (N_DIM / 128));
    w8a16_gemm_fb_kernel<<<grid, 256, 0, stream>>>(A, Qw, Sc, Out);
  }
}